// Round 5
// baseline (708.908 us; speedup 1.0000x reference)
//
#include <hip/hip_runtime.h>
#include <math.h>

#define HW 65536
#define DD 160
#define NB 2
#define DCH 40
#define NSL (DCH + 6)   // 46 marched slices per chunk incl. halo
#define NCH 4
#define TW 32
#define TH 16
#define HALOH 22        // TH + 6
#define PITCH 26        // h-pitch of transposed LDS tile (gcd(26,32)=2 -> 2-way, free)

#define SSIM_C1 1e-4f
#define SSIM_C2 9e-4f

struct Gw { float g[7]; };

// Fused SSIM3D v5: 256-thread blocks (4 waves), 4 blocks/CU for wave residency.
// Per block: 32w x 16h tile marching a 40-slice D-chunk. Direct global reads
// (clamped+masked, one-slice register pipeline), W-conv -> transposed
// double-buffered LDS, H-conv + 7-deep D-ring + SSIM, one barrier per slice.
__global__ __launch_bounds__(256, 4) void k_fused(
    const float* __restrict__ img1, const float* __restrict__ img2,
    Gw gw, float* __restrict__ partials)
{
    __shared__ float b1t[2][5][TW][PITCH];   // [buf][field][w][h]
    __shared__ float red[256];

    const int tid = threadIdx.x;
    const int nb = blockIdx.z >> 2;
    const int o0 = (blockIdx.z & 3) * DCH;
    const int h0 = blockIdx.y * TH;
    const int w0 = blockIdx.x * TW;
    const float* i1 = img1 + (size_t)nb * DD * HW;
    const float* i2 = img2 + (size_t)nb * DD * HW;

    // ---- W-thread geometry (tid < 176): row hh (0..21), 4 outputs at wb ----
    const bool wth = (tid < 176);
    const int hh = tid >> 3;
    const int wb = (tid & 7) * 4;
    const int gh = h0 - 3 + hh;
    const int gwb = w0 - 3 + wb;
    const bool ghv = wth && ((unsigned)gh < 256u);
    const int ghc = gh < 0 ? 0 : (gh > 255 ? 255 : gh);
    int coff[10];
    float msk[10];
#pragma unroll
    for (int i = 0; i < 10; ++i) {
        int gwi = gwb + i;
        int gc = gwi < 0 ? 0 : (gwi > 255 ? 255 : gwi);
        coff[i] = ghc * 256 + gc;                    // always-in-bounds address
        msk[i] = (ghv && gwi == gc) ? 1.f : 0.f;     // zero-pad mask
    }

    // ---- H/D geometry: all 256 threads, 2 output rows each ----
    const int wcol = tid & 31;
    const int hb = (tid >> 5) * 2;   // 0..14

    float ring[2][5][7] = {};
    float lsum = 0.f;
    float cx[10], cy[10];

    // prologue: load slice r=0 (s = o0-3)
    {
        const int s0 = o0 - 3;
        if (s0 >= 0 && wth) {
            const float* p1 = i1 + (size_t)s0 * HW;
            const float* p2 = i2 + (size_t)s0 * HW;
#pragma unroll
            for (int i = 0; i < 10; ++i) {
                cx[i] = p1[coff[i]] * msk[i];
                cy[i] = p2[coff[i]] * msk[i];
            }
        }
    }

    for (int t = 0; t < 7; ++t) {
#pragma unroll
        for (int p = 0; p < 7; ++p) {
            const int r = 7 * t + p;
            if (r <= NSL) {
                const int scur = o0 - 3 + r;
                const bool wv = (r < NSL) && (scur >= 0) && (scur < DD);
                const int snx = scur + 1;
                const bool pfv = (r + 1 < NSL) && (snx >= 0) && (snx < DD);

                // 1) issue next slice's global loads (consumed at iteration end)
                float pfx[10], pfy[10];
                if (pfv && wth) {
                    const float* p1 = i1 + (size_t)snx * HW;
                    const float* p2 = i2 + (size_t)snx * HW;
#pragma unroll
                    for (int i = 0; i < 10; ++i) pfx[i] = p1[coff[i]];
#pragma unroll
                    for (int i = 0; i < 10; ++i) pfy[i] = p2[coff[i]];
                }

                // 2) W-pass from registers -> b1t[r&1]
                if (wv && wth) {
                    float a[4][5] = {};
#pragma unroll
                    for (int i = 0; i < 10; ++i) {
                        const float xx = cx[i] * cx[i];
                        const float yy = cy[i] * cy[i];
                        const float xy = cx[i] * cy[i];
#pragma unroll
                        for (int o = 0; o < 4; ++o) {
                            const int k = i - o;
                            if (k >= 0 && k < 7) {
                                const float gk = gw.g[k];
                                a[o][0] += gk * cx[i];
                                a[o][1] += gk * cy[i];
                                a[o][2] += gk * xx;
                                a[o][3] += gk * yy;
                                a[o][4] += gk * xy;
                            }
                        }
                    }
                    float* bb = &b1t[r & 1][0][0][0];
#pragma unroll
                    for (int f = 0; f < 5; ++f)
#pragma unroll
                        for (int o = 0; o < 4; ++o)
                            bb[f * (TW * PITCH) + (wb + o) * PITCH + hh] = a[o][f];
                }

                // 3) H-pass + D-ring + SSIM for slice rp = r-1 (other buffer)
                if (r >= 1) {
                    const int rp = r - 1;
                    const int sp = o0 - 3 + rp;
                    const int pi = (p + 6) % 7;   // == rp % 7, compile-time
                    if (sp >= 0 && sp < DD) {
                        const float* br = &b1t[rp & 1][0][0][0];
#pragma unroll
                        for (int f = 0; f < 5; ++f) {
                            float v[8];
#pragma unroll
                            for (int i = 0; i < 8; ++i)
                                v[i] = br[f * (TW * PITCH) + wcol * PITCH + hb + i];
#pragma unroll
                            for (int o = 0; o < 2; ++o) {
                                float acc = 0.f;
#pragma unroll
                                for (int k = 0; k < 7; ++k) acc += gw.g[k] * v[o + k];
                                ring[o][f][pi] = acc;
                            }
                        }
                    } else {
#pragma unroll
                        for (int o = 0; o < 2; ++o)
#pragma unroll
                            for (int f = 0; f < 5; ++f) ring[o][f][pi] = 0.f;
                    }
                    if (r >= 7) {
#pragma unroll
                        for (int o = 0; o < 2; ++o) {
                            float c0 = 0.f, c1 = 0.f, c2 = 0.f, c3 = 0.f, c4 = 0.f;
#pragma unroll
                            for (int k = 0; k < 7; ++k) {
                                const float gk = gw.g[k];
                                const int pp = (pi + 1 + k) % 7;
                                c0 += gk * ring[o][0][pp];
                                c1 += gk * ring[o][1][pp];
                                c2 += gk * ring[o][2][pp];
                                c3 += gk * ring[o][3][pp];
                                c4 += gk * ring[o][4][pp];
                            }
                            const float mu1 = c0, mu2 = c1;
                            const float mu1s = mu1 * mu1, mu2s = mu2 * mu2, m12 = mu1 * mu2;
                            const float s1 = c2 - mu1s, s2 = c3 - mu2s, s12 = c4 - m12;
                            const float num = (2.f * m12 + SSIM_C1) * (2.f * s12 + SSIM_C2);
                            const float den = (mu1s + mu2s + SSIM_C1) * (s1 + s2 + SSIM_C2);
                            lsum += num / den;
                        }
                    }
                }

                // 4) register handoff
                if (pfv && wth) {
#pragma unroll
                    for (int i = 0; i < 10; ++i) {
                        cx[i] = pfx[i] * msk[i];
                        cy[i] = pfy[i] * msk[i];
                    }
                }
                __syncthreads();
            }
        }
    }

    // deterministic block reduction
    red[tid] = lsum;
    __syncthreads();
    for (int off = 128; off > 0; off >>= 1) {
        if (tid < off) red[tid] += red[tid + off];
        __syncthreads();
    }
    if (tid == 0)
        partials[(blockIdx.z * gridDim.y + blockIdx.y) * gridDim.x + blockIdx.x] = red[0];
}

__global__ __launch_bounds__(256) void k_final(
    const float* __restrict__ partials, int n, float scale, float* __restrict__ out)
{
    __shared__ float red[256];
    float s = 0.f;
    for (int i = threadIdx.x; i < n; i += 256) s += partials[i];
    red[threadIdx.x] = s;
    __syncthreads();
    for (int off = 128; off > 0; off >>= 1) {
        if (threadIdx.x < off) red[threadIdx.x] += red[threadIdx.x + off];
        __syncthreads();
    }
    if (threadIdx.x == 0) out[0] = red[0] * scale;
}

extern "C" void kernel_launch(void* const* d_in, const int* in_sizes, int n_in,
                              void* d_out, int out_size, void* d_ws, size_t ws_size,
                              hipStream_t stream)
{
    const float* img1 = (const float*)d_in[0];
    const float* img2 = (const float*)d_in[1];
    float* out = (float*)d_out;
    float* partials = (float*)d_ws;

    Gw gw;
    {
        double gs[7], sum = 0.0;
        for (int i = 0; i < 7; ++i) { double x = i - 3; gs[i] = exp(-x * x / 4.5); sum += gs[i]; }
        for (int i = 0; i < 7; ++i) gw.g[i] = (float)(gs[i] / sum);
    }

    dim3 grid(256 / TW, 256 / TH, NB * NCH);   // 8 x 16 x 8 = 1024 blocks -> 4/CU
    k_fused<<<grid, dim3(256), 0, stream>>>(img1, img2, gw, partials);
    k_final<<<dim3(1), dim3(256), 0, stream>>>(
        partials, (256 / TW) * (256 / TH) * NB * NCH, (float)(1.0 / 20971520.0), out);
}

// Round 6
// 200.101 us; speedup vs baseline: 3.5427x; 3.5427x over previous
//
#include <hip/hip_runtime.h>
#include <math.h>

#define HW 65536
#define DD 160
#define NB 2
#define DCH 40
#define NSL (DCH + 6)   // 46 marched slices per chunk incl. halo
#define NCH 4
#define TW 32
#define TH 16
#define PITCH 26        // h-pitch of transposed LDS tile

#define SSIM_C1 1e-4f
#define SSIM_C2 9e-4f

struct Gw { float g[7]; };

// Fused SSIM3D v6: 256-thread blocks, 1024 blocks (4/CU). Direct global reads,
// prefetch-into-consumed-registers (no separate pf regs), bitmask W zero-pad,
// transposed double-buffered LDS intermediate, one barrier per slice.
__global__ __launch_bounds__(256, 2) void k_fused(
    const float* __restrict__ img1, const float* __restrict__ img2,
    Gw gw, float* __restrict__ partials)
{
    __shared__ float b1t[2][5][TW][PITCH];   // [buf][field][w][h]
    __shared__ float red[256];

    const int tid = threadIdx.x;
    const int nb = blockIdx.z >> 2;
    const int o0 = (blockIdx.z & 3) * DCH;
    const int h0 = blockIdx.y * TH;
    const int w0 = blockIdx.x * TW;
    const float* i1 = img1 + (size_t)nb * DD * HW;
    const float* i2 = img2 + (size_t)nb * DD * HW;

    // ---- W-thread geometry (tid < 176): row hh (0..21), 4 outputs at wb ----
    const bool wth = (tid < 176);
    const int hh = tid >> 3;
    const int wb = (tid & 7) * 4;
    const int gh = h0 - 3 + hh;
    const int gwb = w0 - 3 + wb;
    const bool ghv = wth && ((unsigned)gh < 256u);
    const int ghc = gh < 0 ? 0 : (gh > 255 ? 255 : gh);
    int coff[10];
    unsigned wbits = 0;
#pragma unroll
    for (int i = 0; i < 10; ++i) {
        int gwi = gwb + i;
        int gc = gwi < 0 ? 0 : (gwi > 255 ? 255 : gwi);
        coff[i] = ghc * 256 + gc;                        // always-in-bounds address
        if (ghv && gwi == gc) wbits |= (1u << i);        // zero-pad mask bit
    }

    // ---- H/D geometry: all 256 threads, 2 output rows each ----
    const int wcol = tid & 31;
    const int hb = (tid >> 5) * 2;   // 0..14

    float ring[2][5][7] = {};
    float lsum = 0.f;
    float cx[10], cy[10];

    // prologue: load slice r=0 (s = o0-3)
    {
        const int s0 = o0 - 3;
        if (s0 >= 0 && wth) {
            const float* p1 = i1 + (size_t)s0 * HW;
            const float* p2 = i2 + (size_t)s0 * HW;
#pragma unroll
            for (int i = 0; i < 10; ++i) {
                cx[i] = p1[coff[i]];
                cy[i] = p2[coff[i]];
            }
        }
    }

    for (int t = 0; t < 7; ++t) {
#pragma unroll
        for (int p = 0; p < 7; ++p) {
            const int r = 7 * t + p;
            if (r <= NSL) {
                const int scur = o0 - 3 + r;
                const bool wv = (r < NSL) && (scur >= 0) && (scur < DD);
                const int snx = scur + 1;
                const bool pfv = (r + 1 < NSL) && (snx >= 0) && (snx < DD);

                // 1) W-pass from registers -> b1t[r&1] (masked at consumption)
                if (wv && wth) {
                    float a[4][5] = {};
#pragma unroll
                    for (int i = 0; i < 10; ++i) {
                        const float xi = (wbits & (1u << i)) ? cx[i] : 0.f;
                        const float yi = (wbits & (1u << i)) ? cy[i] : 0.f;
                        const float xx = xi * xi;
                        const float yy = yi * yi;
                        const float xy = xi * yi;
#pragma unroll
                        for (int o = 0; o < 4; ++o) {
                            const int k = i - o;
                            if (k >= 0 && k < 7) {
                                const float gk = gw.g[k];
                                a[o][0] += gk * xi;
                                a[o][1] += gk * yi;
                                a[o][2] += gk * xx;
                                a[o][3] += gk * yy;
                                a[o][4] += gk * xy;
                            }
                        }
                    }
                    float* bb = &b1t[r & 1][0][0][0];
#pragma unroll
                    for (int f = 0; f < 5; ++f)
#pragma unroll
                        for (int o = 0; o < 4; ++o)
                            bb[f * (TW * PITCH) + (wb + o) * PITCH + hh] = a[o][f];
                }

                // 2) prefetch next slice directly into cx/cy (consumed next iter;
                //    latency hides under H-pass + D-conv + barrier)
                if (pfv && wth) {
                    const float* p1 = i1 + (size_t)snx * HW;
                    const float* p2 = i2 + (size_t)snx * HW;
#pragma unroll
                    for (int i = 0; i < 10; ++i) cx[i] = p1[coff[i]];
#pragma unroll
                    for (int i = 0; i < 10; ++i) cy[i] = p2[coff[i]];
                }

                // 3) H-pass + D-ring + SSIM for slice rp = r-1 (other buffer)
                if (r >= 1) {
                    const int rp = r - 1;
                    const int sp = o0 - 3 + rp;
                    const int pi = (p + 6) % 7;   // == rp % 7, compile-time
                    if (sp >= 0 && sp < DD) {
                        const float* br = &b1t[rp & 1][0][0][0];
#pragma unroll
                        for (int f = 0; f < 5; ++f) {
                            float v[8];
#pragma unroll
                            for (int i = 0; i < 8; ++i)
                                v[i] = br[f * (TW * PITCH) + wcol * PITCH + hb + i];
#pragma unroll
                            for (int o = 0; o < 2; ++o) {
                                float acc = 0.f;
#pragma unroll
                                for (int k = 0; k < 7; ++k) acc += gw.g[k] * v[o + k];
                                ring[o][f][pi] = acc;
                            }
                        }
                    } else {
#pragma unroll
                        for (int o = 0; o < 2; ++o)
#pragma unroll
                            for (int f = 0; f < 5; ++f) ring[o][f][pi] = 0.f;
                    }
                    if (r >= 7) {
#pragma unroll
                        for (int o = 0; o < 2; ++o) {
                            float c0 = 0.f, c1 = 0.f, c2 = 0.f, c3 = 0.f, c4 = 0.f;
#pragma unroll
                            for (int k = 0; k < 7; ++k) {
                                const float gk = gw.g[k];
                                const int pp = (pi + 1 + k) % 7;
                                c0 += gk * ring[o][0][pp];
                                c1 += gk * ring[o][1][pp];
                                c2 += gk * ring[o][2][pp];
                                c3 += gk * ring[o][3][pp];
                                c4 += gk * ring[o][4][pp];
                            }
                            const float mu1 = c0, mu2 = c1;
                            const float mu1s = mu1 * mu1, mu2s = mu2 * mu2, m12 = mu1 * mu2;
                            const float s1 = c2 - mu1s, s2 = c3 - mu2s, s12 = c4 - m12;
                            const float num = (2.f * m12 + SSIM_C1) * (2.f * s12 + SSIM_C2);
                            const float den = (mu1s + mu2s + SSIM_C1) * (s1 + s2 + SSIM_C2);
                            lsum += num / den;
                        }
                    }
                }
                __syncthreads();
            }
        }
    }

    // deterministic block reduction
    red[tid] = lsum;
    __syncthreads();
    for (int off = 128; off > 0; off >>= 1) {
        if (tid < off) red[tid] += red[tid + off];
        __syncthreads();
    }
    if (tid == 0)
        partials[(blockIdx.z * gridDim.y + blockIdx.y) * gridDim.x + blockIdx.x] = red[0];
}

__global__ __launch_bounds__(256) void k_final(
    const float* __restrict__ partials, int n, float scale, float* __restrict__ out)
{
    __shared__ float red[256];
    float s = 0.f;
    for (int i = threadIdx.x; i < n; i += 256) s += partials[i];
    red[threadIdx.x] = s;
    __syncthreads();
    for (int off = 128; off > 0; off >>= 1) {
        if (threadIdx.x < off) red[threadIdx.x] += red[threadIdx.x + off];
        __syncthreads();
    }
    if (threadIdx.x == 0) out[0] = red[0] * scale;
}

extern "C" void kernel_launch(void* const* d_in, const int* in_sizes, int n_in,
                              void* d_out, int out_size, void* d_ws, size_t ws_size,
                              hipStream_t stream)
{
    const float* img1 = (const float*)d_in[0];
    const float* img2 = (const float*)d_in[1];
    float* out = (float*)d_out;
    float* partials = (float*)d_ws;

    Gw gw;
    {
        double gs[7], sum = 0.0;
        for (int i = 0; i < 7; ++i) { double x = i - 3; gs[i] = exp(-x * x / 4.5); sum += gs[i]; }
        for (int i = 0; i < 7; ++i) gw.g[i] = (float)(gs[i] / sum);
    }

    dim3 grid(256 / TW, 256 / TH, NB * NCH);   // 8 x 16 x 8 = 1024 blocks -> 4/CU
    k_fused<<<grid, dim3(256), 0, stream>>>(img1, img2, gw, partials);
    k_final<<<dim3(1), dim3(256), 0, stream>>>(
        partials, (256 / TW) * (256 / TH) * NB * NCH, (float)(1.0 / 20971520.0), out);
}

// Round 7
// 152.061 us; speedup vs baseline: 4.6620x; 1.3159x over previous
//
#include <hip/hip_runtime.h>
#include <math.h>

#define HW 65536
#define DD 160
#define NB 2
#define DCH 40
#define NSL (DCH + 6)   // 46 marched slices per chunk incl. halo
#define NCH 4
#define TW 32
#define TH 16
#define PH 23           // h-pitch (odd -> 2-way LDS access, free)

#define SSIM_C1 1e-4f
#define SSIM_C2 9e-4f

typedef float f32x2 __attribute__((ext_vector_type(2)));

struct Gw { float g[7]; };

static __device__ __forceinline__ f32x2 s2(float v) { f32x2 r; r.x = v; r.y = v; return r; }

// Fused SSIM3D v7: packed-fp32 (v_pk_fma_f32) field pairing.
// Fields (x,y) and (xx,yy) live as float2 through all three conv passes;
// xy stays scalar. LDS: two float2 planes + one float plane, double-buffered.
// 256-thread blocks, 1024 blocks, one barrier per slice, rcp instead of fdiv.
__global__ __launch_bounds__(256, 2) void k_fused(
    const float* __restrict__ img1, const float* __restrict__ img2,
    Gw gw, float* __restrict__ partials)
{
    __shared__ f32x2 pA[2][TW][PH];   // (conv_w x, conv_w y)
    __shared__ f32x2 pB[2][TW][PH];   // (conv_w xx, conv_w yy)
    __shared__ float pC[2][TW][PH];   // conv_w xy
    __shared__ float red[256];

    const int tid = threadIdx.x;
    const int nb = blockIdx.z >> 2;
    const int o0 = (blockIdx.z & 3) * DCH;
    const int h0 = blockIdx.y * TH;
    const int w0 = blockIdx.x * TW;
    const float* i1 = img1 + (size_t)nb * DD * HW;
    const float* i2 = img2 + (size_t)nb * DD * HW;

    // ---- W-thread geometry (tid < 176): row hh (0..21), 4 outputs at wb ----
    const bool wth = (tid < 176);
    const int hh = tid >> 3;
    const int wb = (tid & 7) * 4;
    const int gh = h0 - 3 + hh;
    const int gwb = w0 - 3 + wb;
    const bool ghv = wth && ((unsigned)gh < 256u);
    const int ghc = gh < 0 ? 0 : (gh > 255 ? 255 : gh);
    int coff[10];
    unsigned wbits = 0;
#pragma unroll
    for (int i = 0; i < 10; ++i) {
        int gwi = gwb + i;
        int gc = gwi < 0 ? 0 : (gwi > 255 ? 255 : gwi);
        coff[i] = ghc * 256 + gc;                 // always-in-bounds address
        if (ghv && gwi == gc) wbits |= (1u << i); // zero-pad mask bit
    }

    // ---- H/D geometry: all 256 threads, 2 output rows each ----
    const int wcol = tid & 31;
    const int hb = (tid >> 5) * 2;   // 0..14

    f32x2 ringA[2][7] = {};
    f32x2 ringB[2][7] = {};
    float ringC[2][7] = {};
    float lsum = 0.f;
    f32x2 cxy[10];

    // prologue: load slice r=0 (s = o0-3)
    {
        const int s0 = o0 - 3;
        if (s0 >= 0 && wth) {
            const float* p1 = i1 + (size_t)s0 * HW;
            const float* p2 = i2 + (size_t)s0 * HW;
#pragma unroll
            for (int i = 0; i < 10; ++i) {
                cxy[i].x = p1[coff[i]];
                cxy[i].y = p2[coff[i]];
            }
        }
    }

    for (int t = 0; t < 7; ++t) {
#pragma unroll
        for (int p = 0; p < 7; ++p) {
            const int r = 7 * t + p;
            if (r <= NSL) {
                const int scur = o0 - 3 + r;
                const bool wv = (r < NSL) && (scur >= 0) && (scur < DD);
                const int snx = scur + 1;
                const bool pfv = (r + 1 < NSL) && (snx >= 0) && (snx < DD);

                // 1) W-pass from registers -> planes[r&1] (masked at consumption)
                if (wv && wth) {
                    f32x2 aA[4] = {};
                    f32x2 aB[4] = {};
                    float aC[4] = {};
#pragma unroll
                    for (int i = 0; i < 10; ++i) {
                        const f32x2 xi2 = ((wbits >> i) & 1u) ? cxy[i] : s2(0.f);
                        const f32x2 xx2 = xi2 * xi2;      // v_pk_mul_f32
                        const float xy = xi2.x * xi2.y;
#pragma unroll
                        for (int o = 0; o < 4; ++o) {
                            const int k = i - o;
                            if (k >= 0 && k < 7) {
                                const float gk = gw.g[k];
                                aA[o] += s2(gk) * xi2;    // v_pk_fma_f32
                                aB[o] += s2(gk) * xx2;
                                aC[o] += gk * xy;
                            }
                        }
                    }
                    const int buf = r & 1;
#pragma unroll
                    for (int o = 0; o < 4; ++o) {
                        pA[buf][wb + o][hh] = aA[o];
                        pB[buf][wb + o][hh] = aB[o];
                        pC[buf][wb + o][hh] = aC[o];
                    }
                }

                // 2) prefetch next slice directly into cxy (consumed next iter)
                if (pfv && wth) {
                    const float* p1 = i1 + (size_t)snx * HW;
                    const float* p2 = i2 + (size_t)snx * HW;
#pragma unroll
                    for (int i = 0; i < 10; ++i) cxy[i].x = p1[coff[i]];
#pragma unroll
                    for (int i = 0; i < 10; ++i) cxy[i].y = p2[coff[i]];
                }

                // 3) H-pass + D-ring + SSIM for slice rp = r-1 (other buffer)
                if (r >= 1) {
                    const int rp = r - 1;
                    const int sp = o0 - 3 + rp;
                    const int pi = (p + 6) % 7;   // == rp % 7, compile-time
                    if (sp >= 0 && sp < DD) {
                        const int buf = rp & 1;
                        f32x2 vA[8], vB[8];
                        float vC[8];
#pragma unroll
                        for (int i = 0; i < 8; ++i) {
                            vA[i] = pA[buf][wcol][hb + i];
                            vB[i] = pB[buf][wcol][hb + i];
                            vC[i] = pC[buf][wcol][hb + i];
                        }
#pragma unroll
                        for (int o = 0; o < 2; ++o) {
                            f32x2 aA = s2(0.f), aB = s2(0.f);
                            float aC = 0.f;
#pragma unroll
                            for (int k = 0; k < 7; ++k) {
                                const float gk = gw.g[k];
                                aA += s2(gk) * vA[o + k];
                                aB += s2(gk) * vB[o + k];
                                aC += gk * vC[o + k];
                            }
                            ringA[o][pi] = aA;
                            ringB[o][pi] = aB;
                            ringC[o][pi] = aC;
                        }
                    } else {
#pragma unroll
                        for (int o = 0; o < 2; ++o) {
                            ringA[o][pi] = s2(0.f);
                            ringB[o][pi] = s2(0.f);
                            ringC[o][pi] = 0.f;
                        }
                    }
                    if (r >= 7) {
#pragma unroll
                        for (int o = 0; o < 2; ++o) {
                            f32x2 cA = s2(0.f), cB = s2(0.f);
                            float cC = 0.f;
#pragma unroll
                            for (int k = 0; k < 7; ++k) {
                                const float gk = gw.g[k];
                                const int pp = (pi + 1 + k) % 7;
                                cA += s2(gk) * ringA[o][pp];
                                cB += s2(gk) * ringB[o][pp];
                                cC += gk * ringC[o][pp];
                            }
                            const float mu1 = cA.x, mu2 = cA.y;
                            const float mu1s = mu1 * mu1, mu2s = mu2 * mu2, m12 = mu1 * mu2;
                            const float s1 = cB.x - mu1s, s2v = cB.y - mu2s, s12 = cC - m12;
                            const float num = (2.f * m12 + SSIM_C1) * (2.f * s12 + SSIM_C2);
                            const float den = (mu1s + mu2s + SSIM_C1) * (s1 + s2v + SSIM_C2);
                            lsum += num * __builtin_amdgcn_rcpf(den);
                        }
                    }
                }
                __syncthreads();
            }
        }
    }

    // deterministic block reduction
    red[tid] = lsum;
    __syncthreads();
    for (int off = 128; off > 0; off >>= 1) {
        if (tid < off) red[tid] += red[tid + off];
        __syncthreads();
    }
    if (tid == 0)
        partials[(blockIdx.z * gridDim.y + blockIdx.y) * gridDim.x + blockIdx.x] = red[0];
}

__global__ __launch_bounds__(256) void k_final(
    const float* __restrict__ partials, int n, float scale, float* __restrict__ out)
{
    __shared__ float red[256];
    float s = 0.f;
    for (int i = threadIdx.x; i < n; i += 256) s += partials[i];
    red[threadIdx.x] = s;
    __syncthreads();
    for (int off = 128; off > 0; off >>= 1) {
        if (threadIdx.x < off) red[threadIdx.x] += red[threadIdx.x + off];
        __syncthreads();
    }
    if (threadIdx.x == 0) out[0] = red[0] * scale;
}

extern "C" void kernel_launch(void* const* d_in, const int* in_sizes, int n_in,
                              void* d_out, int out_size, void* d_ws, size_t ws_size,
                              hipStream_t stream)
{
    const float* img1 = (const float*)d_in[0];
    const float* img2 = (const float*)d_in[1];
    float* out = (float*)d_out;
    float* partials = (float*)d_ws;

    Gw gw;
    {
        double gs[7], sum = 0.0;
        for (int i = 0; i < 7; ++i) { double x = i - 3; gs[i] = exp(-x * x / 4.5); sum += gs[i]; }
        for (int i = 0; i < 7; ++i) gw.g[i] = (float)(gs[i] / sum);
    }

    dim3 grid(256 / TW, 256 / TH, NB * NCH);   // 8 x 16 x 8 = 1024 blocks
    k_fused<<<grid, dim3(256), 0, stream>>>(img1, img2, gw, partials);
    k_final<<<dim3(1), dim3(256), 0, stream>>>(
        partials, (256 / TW) * (256 / TH) * NB * NCH, (float)(1.0 / 20971520.0), out);
}